// Round 7
// baseline (332.789 us; speedup 1.0000x reference)
//
#include <hip/hip_runtime.h>

// DISCO S2 conv, equiangular 360x720 -> 180x360, K=3, B*C=128.
// out[bc, k*180+t, p] = sum_{e in seg(k,t)} val[e]*qw[lat[e]] * x[bc, lat[e], (lon[e]-2p-2) mod 720]
//
// Round-7: k-merged hot loop (entry dedup across the 3 kernel offsets).
//  - k1 list is PRIMARY: prep bakes cf-triple {cf0,cf1,cf2} per entry (partners
//    located by exact binary search in k0/k2 rows). One ds_read_b128 -> 12 FMA.
//  - k0/k2 lists processed only for entries NOT in k1 (validity bit baked in
//    offset bit0; wave-uniform branch). Exactness relies only on list
//    membership, never on analytic geometry.
//  - constant-val full rows (poles) collapse to rowsum (triple-cf apply).
//  - MAXR=2 -> 27.1 KB LDS -> 5 blocks/CU (30 waves) for latency hiding.
//  - per-wave baked LDS offsets + 64-slot wrap mirror (no mod/decode in loop).

#define NLAT_IN  360
#define NLON_IN  720
#define NLAT_OUT 180
#define NLON_OUT 360
#define KSIZE    3
#define NSEG     (KSIZE * NLAT_OUT)    // 540
#define CHW      (NLAT_IN * NLON_IN)   // 259200
#define BCTOT    128
#define G        4
#define NBCG     (BCTOT / G)           // 32
#define MAXR     2
#define PH       10
#define NTHREADS 384
#define NWAVES   (NTHREADS / 64)
#define SLOTS    424                   // 360 + 64 wrap mirror
#define ROWB     (SLOTS * 16)          // 6784 B per row-parity plane

// ---------------- device helpers ----------------

__device__ __forceinline__ int lbw(const int* __restrict__ v, int a, int b, int w) {
    while (a < b) { int m = (a + b) >> 1; if (v[m] < w) a = m + 1; else b = m; }
    return a;
}

// index of (h,w) in segment s's list, or -1.
__device__ __forceinline__ int find_in(const int* __restrict__ lon,
                                       const int* __restrict__ ptrh,
                                       const int* __restrict__ hbase,
                                       int s, int h, int w) {
    int j = h - hbase[s];
    if (j < 0 || j >= PH - 1) return -1;
    int a = ptrh[s * PH + j], b = ptrh[s * PH + j + 1];
    int i = lbw(lon, a, b, w);
    return (i < b && lon[i] == w) ? i : -1;
}

// ---------------- prep kernels ----------------

// per (s,j): ptrh row sub-pointers + hbase/hlast (binary searches on seg/lat).
__global__ void prep1_kernel(const int* __restrict__ seg, const int* __restrict__ lat,
                             int nnz, int* __restrict__ ptrh, int* __restrict__ hbase,
                             int* __restrict__ hlast) {
    int idx = blockIdx.x * blockDim.x + threadIdx.x;
    if (idx >= NSEG * PH) return;
    int s = idx / PH, j = idx - s * PH;
    int lo = 0, hi = nnz;
    while (lo < hi) { int m = (lo + hi) >> 1; if (seg[m] < s) lo = m + 1; else hi = m; }
    int e0 = lo;
    lo = e0; hi = nnz;
    while (lo < hi) { int m = (lo + hi) >> 1; if (seg[m] < s + 1) lo = m + 1; else hi = m; }
    int e1 = lo;
    if (e0 >= e1) {
        ptrh[idx] = e0;
        if (j == 0) { hbase[s] = 1 << 28; hlast[s] = -(1 << 28); }
        return;
    }
    int hb = lat[e0];
    if (j == 0) { hbase[s] = hb; hlast[s] = lat[e1 - 1]; }
    int tg = hb + j;
    lo = e0; hi = e1;
    while (lo < hi) { int m = (lo + hi) >> 1; if (lat[m] < tg) lo = m + 1; else hi = m; }
    ptrh[idx] = lo;
}

// per t: union row span over the 3 segments.
__global__ void span_kernel(const int* __restrict__ hbase, const int* __restrict__ hlast,
                            int* __restrict__ hbU, int* __restrict__ hlU) {
    int t = blockIdx.x * blockDim.x + threadIdx.x;
    if (t >= NLAT_OUT) return;
    int lo = 1 << 28, hi = -(1 << 28);
#pragma unroll
    for (int k = 0; k < KSIZE; ++k) {
        lo = min(lo, hbase[k * NLAT_OUT + t]);
        hi = max(hi, hlast[k * NLAT_OUT + t]);
    }
    hbU[t] = lo; hlU[t] = hi;
}

// per (s,j): collapse flag = full 720 row + constant val + (k==1 or not-in-k1).
__global__ void flags_kernel(const int* __restrict__ lon, const float* __restrict__ val,
                             const int* __restrict__ ptrh, const int* __restrict__ hbase,
                             int* __restrict__ flags) {
    int idx = blockIdx.x * blockDim.x + threadIdx.x;
    if (idx >= NSEG * PH) return;
    int s = idx / PH, j = idx - s * PH;
    int f = 0;
    if (j < PH - 1) {
        int a = ptrh[idx], b = ptrh[idx + 1];
        if (b - a == NLON_IN) {
            float v0 = val[a], v1 = val[a + 240], v2 = val[a + 480];
            float d = fmaxf(fabsf(v0 - v1), fmaxf(fabsf(v0 - v2), fabsf(v1 - v2)));
            if (d < 1e-5f) {
                int k = s / NLAT_OUT;
                if (k == 1) f = 1;
                else {
                    int t = s - k * NLAT_OUT;
                    int row = hbase[s] + j;
                    f = (find_in(lon, ptrh, hbase, NLAT_OUT + t, row, lon[a]) < 0) ? 1 : 0;
                }
            }
        }
    }
    flags[idx] = f;
}

// per entry: cf-triple + per-wave baked LDS offsets (validity in bit0 for k0/k2).
__global__ void meta_kernel(const int* __restrict__ seg, const int* __restrict__ lat,
                            const int* __restrict__ lon, const float* __restrict__ val,
                            const float* __restrict__ qw, const int* __restrict__ ptrh,
                            const int* __restrict__ hbase, const int* __restrict__ hbU,
                            int nnz, int nnzpad,
                            uint4* __restrict__ cf3, unsigned* __restrict__ off6) {
    int e = blockIdx.x * blockDim.x + threadIdx.x;
    if (e >= nnz) return;
    int s = seg[e], h = lat[e], w = lon[e];
    int k = s / NLAT_OUT, t = s - k * NLAT_OUT;
    float cfo = val[e] * qw[h];
    float c0 = 0.f, c1 = 0.f, c2 = 0.f;
    unsigned vbit = 0u;
    if (k == 1) {
        c1 = cfo;
        int i0 = find_in(lon, ptrh, hbase, t, h, w);
        if (i0 >= 0) c0 = val[i0] * qw[h];
        int i2 = find_in(lon, ptrh, hbase, 2 * NLAT_OUT + t, h, w);
        if (i2 >= 0) c2 = val[i2] * qw[h];
    } else {
        int i1 = find_in(lon, ptrh, hbase, NLAT_OUT + t, h, w);
        vbit = (i1 < 0) ? 1u : 0u;   // valid iff NOT a duplicate of a k1 entry
        if (k == 0) c0 = cfo; else c2 = cfo;
    }
    cf3[e] = make_uint4(__float_as_uint(c0), __float_as_uint(c1), __float_as_uint(c2), 0u);
    int rp = ((h - hbU[t]) % MAXR) * 2 + (w & 1);
    int i0w = w >> 1;
    int s0 = i0w ? (i0w - 1) : (NLON_OUT - 1);
    unsigned base = (unsigned)(rp * ROWB);
    for (int wid = 0; wid < NWAVES; ++wid) {
        int b0 = s0 + 720 - 63 - 64 * wid;
        if (b0 >= 720) b0 -= 720;
        if (b0 >= 360) b0 -= 360;
        unsigned off = base + ((unsigned)b0 << 4);
        if (k != 1) off |= vbit;
        off6[(size_t)wid * nnzpad + e] = off;
    }
}

// ---------------- main kernel ----------------

__global__ __launch_bounds__(NTHREADS) void disco_kernel(
    const float*    __restrict__ x,
    const uint4*    __restrict__ cf3,
    const unsigned* __restrict__ off6,
    const int*      __restrict__ ptrh,
    const int*      __restrict__ hbase,
    const int*      __restrict__ flags,
    const int*      __restrict__ hbU,
    const int*      __restrict__ hlU,
    int nnzpad,
    float*          __restrict__ out)
{
    __shared__ float4 ldsx[MAXR * 2][SLOTS];      // 27,136 B -> 5 blocks/CU
    __shared__ float4 rsum_s;
    __shared__ float4 wred[NWAVES];

    const int tid  = threadIdx.x;
    const int lane = tid & 63, wid = tid >> 6;
    const int p    = wid * 64 + 63 - lane;        // reversed lane -> ascending slots
    const int bc0  = blockIdx.x * G;
    const int ty   = blockIdx.y;
    const int t    = (ty & 1) ? (NLAT_OUT - 1 - (ty >> 1)) : (ty >> 1);  // poles first

    const int hb0 = hbase[t];
    const int hb1 = hbase[NLAT_OUT + t];
    const int hb2 = hbase[2 * NLAT_OUT + t];
    const int rlo = hbU[t], rhi = hlU[t];

    const unsigned* offp  = off6 + (size_t)wid * nnzpad;
    const char*     lbase = (const char*)&ldsx[0][0];
    const unsigned  loff  = (unsigned)(lane << 4);

    float acc[KSIZE][G] = {};

    for (int r0 = rlo; r0 <= rhi; r0 += MAXR) {
        const int rn = min(MAXR, rhi - r0 + 1);
        __syncthreads();                           // prior window readers done
        // ---- stage rows (4 channels, parity-split, 64-slot wrap mirror) ----
        if (tid < NLON_OUT) {
            for (int r = 0; r < rn; ++r) {
                const float* xr = x + (size_t)bc0 * CHW + (size_t)(r0 + r) * NLON_IN + 2 * tid;
                const float2 v0 = *(const float2*)(xr);
                const float2 v1 = *(const float2*)(xr + CHW);
                const float2 v2 = *(const float2*)(xr + 2 * CHW);
                const float2 v3 = *(const float2*)(xr + 3 * CHW);
                const float4 ev = make_float4(v0.x, v1.x, v2.x, v3.x);
                const float4 ov = make_float4(v0.y, v1.y, v2.y, v3.y);
                ldsx[2 * r + 0][tid] = ev;
                ldsx[2 * r + 1][tid] = ov;
                if (tid < SLOTS - NLON_OUT) {
                    ldsx[2 * r + 0][NLON_OUT + tid] = ev;
                    ldsx[2 * r + 1][NLON_OUT + tid] = ov;
                }
            }
        }
        __syncthreads();
        // ---- rows of this window ----
        for (int r = 0; r < rn; ++r) {
            const int row = r0 + r;
            int aL[3], bL[3], fL[3];
            {
                int j = row - hb0; int ok = (j >= 0) && (j < PH - 1);
                int idx = t * PH + (ok ? j : 0);
                aL[0] = ok ? ptrh[idx] : 0; bL[0] = ok ? ptrh[idx + 1] : 0;
                fL[0] = (ok && bL[0] > aL[0]) ? flags[idx] : 0;
            }
            {
                int j = row - hb1; int ok = (j >= 0) && (j < PH - 1);
                int idx = (NLAT_OUT + t) * PH + (ok ? j : 0);
                aL[1] = ok ? ptrh[idx] : 0; bL[1] = ok ? ptrh[idx + 1] : 0;
                fL[1] = (ok && bL[1] > aL[1]) ? flags[idx] : 0;
            }
            {
                int j = row - hb2; int ok = (j >= 0) && (j < PH - 1);
                int idx = (2 * NLAT_OUT + t) * PH + (ok ? j : 0);
                aL[2] = ok ? ptrh[idx] : 0; bL[2] = ok ? ptrh[idx + 1] : 0;
                fL[2] = (ok && bL[2] > aL[2]) ? flags[idx] : 0;
            }
            const int anyf = fL[0] | fL[1] | fL[2];
            if (anyf) {                            // block-uniform
                float4 v = make_float4(0.f, 0.f, 0.f, 0.f);
                if (tid < NLON_OUT) {
                    const float4 u0 = ldsx[2 * r][tid], u1 = ldsx[2 * r + 1][tid];
                    v = make_float4(u0.x + u1.x, u0.y + u1.y, u0.z + u1.z, u0.w + u1.w);
                }
#pragma unroll
                for (int off = 32; off >= 1; off >>= 1) {
                    v.x += __shfl_down(v.x, off);
                    v.y += __shfl_down(v.y, off);
                    v.z += __shfl_down(v.z, off);
                    v.w += __shfl_down(v.w, off);
                }
                if (lane == 0) wred[wid] = v;
                __syncthreads();
                if (wid == 0) {
                    float4 u = (lane < NWAVES) ? wred[lane] : make_float4(0.f, 0.f, 0.f, 0.f);
#pragma unroll
                    for (int off = 4; off >= 1; off >>= 1) {
                        u.x += __shfl_down(u.x, off);
                        u.y += __shfl_down(u.y, off);
                        u.z += __shfl_down(u.z, off);
                        u.w += __shfl_down(u.w, off);
                    }
                    if (lane == 0) rsum_s = u;
                }
                __syncthreads();
                const float4 rs = rsum_s;
#pragma unroll
                for (int L = 0; L < 3; ++L) {
                    if (fL[L]) {
                        const uint4 c = cf3[aL[L]];
                        const float c0 = __uint_as_float(c.x);
                        const float c1 = __uint_as_float(c.y);
                        const float c2 = __uint_as_float(c.z);
                        acc[0][0] = fmaf(c0, rs.x, acc[0][0]); acc[0][1] = fmaf(c0, rs.y, acc[0][1]);
                        acc[0][2] = fmaf(c0, rs.z, acc[0][2]); acc[0][3] = fmaf(c0, rs.w, acc[0][3]);
                        acc[1][0] = fmaf(c1, rs.x, acc[1][0]); acc[1][1] = fmaf(c1, rs.y, acc[1][1]);
                        acc[1][2] = fmaf(c1, rs.z, acc[1][2]); acc[1][3] = fmaf(c1, rs.w, acc[1][3]);
                        acc[2][0] = fmaf(c2, rs.x, acc[2][0]); acc[2][1] = fmaf(c2, rs.y, acc[2][1]);
                        acc[2][2] = fmaf(c2, rs.z, acc[2][2]); acc[2][3] = fmaf(c2, rs.w, acc[2][3]);
                    }
                }
            }
            // ---- primary (k1) loop: triple-cf, no branch ----
            if (!fL[1] && bL[1] > aL[1]) {
#pragma unroll 4
                for (int e = aL[1]; e < bL[1]; ++e) {
                    const unsigned o  = offp[e];
                    const uint4    c  = cf3[e];
                    const float4   xv = *(const float4*)(lbase + o + loff);
                    const float c0 = __uint_as_float(c.x);
                    const float c1 = __uint_as_float(c.y);
                    const float c2 = __uint_as_float(c.z);
                    acc[0][0] = fmaf(c0, xv.x, acc[0][0]); acc[0][1] = fmaf(c0, xv.y, acc[0][1]);
                    acc[0][2] = fmaf(c0, xv.z, acc[0][2]); acc[0][3] = fmaf(c0, xv.w, acc[0][3]);
                    acc[1][0] = fmaf(c1, xv.x, acc[1][0]); acc[1][1] = fmaf(c1, xv.y, acc[1][1]);
                    acc[1][2] = fmaf(c1, xv.z, acc[1][2]); acc[1][3] = fmaf(c1, xv.w, acc[1][3]);
                    acc[2][0] = fmaf(c2, xv.x, acc[2][0]); acc[2][1] = fmaf(c2, xv.y, acc[2][1]);
                    acc[2][2] = fmaf(c2, xv.z, acc[2][2]); acc[2][3] = fmaf(c2, xv.w, acc[2][3]);
                }
            }
            // ---- k0 residual loop (validity bit) ----
            if (!fL[0] && bL[0] > aL[0]) {
                for (int e = aL[0]; e < bL[0]; ++e) {
                    const unsigned o = offp[e];
                    if (o & 1u) {
                        const float  cf = __uint_as_float(((const unsigned*)cf3)[4 * e + 0]);
                        const float4 xv = *(const float4*)(lbase + (o ^ 1u) + loff);
                        acc[0][0] = fmaf(cf, xv.x, acc[0][0]); acc[0][1] = fmaf(cf, xv.y, acc[0][1]);
                        acc[0][2] = fmaf(cf, xv.z, acc[0][2]); acc[0][3] = fmaf(cf, xv.w, acc[0][3]);
                    }
                }
            }
            // ---- k2 residual loop (validity bit) ----
            if (!fL[2] && bL[2] > aL[2]) {
                for (int e = aL[2]; e < bL[2]; ++e) {
                    const unsigned o = offp[e];
                    if (o & 1u) {
                        const float  cf = __uint_as_float(((const unsigned*)cf3)[4 * e + 2]);
                        const float4 xv = *(const float4*)(lbase + (o ^ 1u) + loff);
                        acc[2][0] = fmaf(cf, xv.x, acc[2][0]); acc[2][1] = fmaf(cf, xv.y, acc[2][1]);
                        acc[2][2] = fmaf(cf, xv.z, acc[2][2]); acc[2][3] = fmaf(cf, xv.w, acc[2][3]);
                    }
                }
            }
        }
    }

    if (p < NLON_OUT) {
#pragma unroll
        for (int k = 0; k < KSIZE; ++k)
#pragma unroll
            for (int g = 0; g < G; ++g)
                out[((size_t)(bc0 + g) * NSEG + k * NLAT_OUT + t) * NLON_OUT + p] = acc[k][g];
    }
}

// ---------------- fallback (tiny ws) ----------------

__global__ void segptr_kernel(const int* __restrict__ seg, int nnz, int* __restrict__ ptr) {
    int s = blockIdx.x * blockDim.x + threadIdx.x;
    if (s > NSEG) return;
    if (s == NSEG) { ptr[NSEG] = nnz; return; }
    int lo = 0, hi = nnz;
    while (lo < hi) { int m = (lo + hi) >> 1; if (seg[m] < s) lo = m + 1; else hi = m; }
    ptr[s] = lo;
}

__global__ __launch_bounds__(384) void disco_simple_kernel(
    const float* __restrict__ x, const float* __restrict__ qw,
    const int* __restrict__ lat, const int* __restrict__ lon,
    const float* __restrict__ val, const int* __restrict__ ptr,
    float* __restrict__ out)
{
    const int p = threadIdx.x;
    if (p >= NLON_OUT) return;
    const int kt = blockIdx.x, bc0 = blockIdx.y * 8;
    const int e0 = ptr[kt], e1 = ptr[kt + 1];
    float acc[8];
#pragma unroll
    for (int g = 0; g < 8; ++g) acc[g] = 0.0f;
    const int pw = 2 * p + 2;
    const float* xb = x + (size_t)bc0 * CHW;
    for (int e = e0; e < e1; ++e) {
        const int h = lat[e], w = lon[e];
        const float cf = val[e] * qw[h];
        int col = w - pw; if (col < 0) col += NLON_IN;
        const float* src = xb + h * NLON_IN + col;
#pragma unroll
        for (int g = 0; g < 8; ++g) acc[g] = fmaf(cf, src[(size_t)g * CHW], acc[g]);
    }
    const size_t ob = ((size_t)bc0 * NSEG + kt) * NLON_OUT + p;
#pragma unroll
    for (int g = 0; g < 8; ++g) out[ob + (size_t)g * NSEG * NLON_OUT] = acc[g];
}

// ---------------- launcher ----------------

extern "C" void kernel_launch(void* const* d_in, const int* in_sizes, int n_in,
                              void* d_out, int out_size, void* d_ws, size_t ws_size,
                              hipStream_t stream)
{
    const float* x   = (const float*)d_in[0];   // [2,64,360,720] f32
    const float* qw  = (const float*)d_in[1];   // [360,1] f32
    const int*   seg = (const int*)  d_in[2];   // [nnz] i32 sorted asc
    const int*   lat = (const int*)  d_in[3];
    const int*   lon = (const int*)  d_in[4];
    const float* val = (const float*)d_in[5];
    const int    nnz = in_sizes[2];
    const int    nnzpad = (nnz + 3) & ~3;

    char* w = (char*)d_ws;
    size_t off = 0;
    int* ptrh  = (int*)(w + off); off += (size_t)NSEG * PH * 4;   // 21600
    int* hbase = (int*)(w + off); off += NSEG * 4;                // 2160
    int* hlast = (int*)(w + off); off += NSEG * 4;                // 2160
    int* flags = (int*)(w + off); off += (size_t)NSEG * PH * 4;   // 21600
    int* hbU   = (int*)(w + off); off += NLAT_OUT * 4;            // 720
    int* hlU   = (int*)(w + off); off += NLAT_OUT * 4;            // 720 -> 48960 (16B mult)
    uint4*    cf3  = (uint4*)(w + off);    off += (size_t)nnzpad * 16;
    unsigned* off6 = (unsigned*)(w + off); off += (size_t)NWAVES * nnzpad * 4;

    if (ws_size < off) {                         // tiny ws: slow-but-correct path
        int* ptr = (int*)d_ws;
        segptr_kernel<<<(NSEG + 1 + 255) / 256, 256, 0, stream>>>(seg, nnz, ptr);
        dim3 grid(NSEG, BCTOT / 8);
        disco_simple_kernel<<<grid, 384, 0, stream>>>(x, qw, lat, lon, val, ptr,
                                                      (float*)d_out);
        return;
    }

    prep1_kernel<<<(NSEG * PH + 255) / 256, 256, 0, stream>>>(seg, lat, nnz,
                                                              ptrh, hbase, hlast);
    span_kernel<<<1, 256, 0, stream>>>(hbase, hlast, hbU, hlU);
    flags_kernel<<<(NSEG * PH + 255) / 256, 256, 0, stream>>>(lon, val, ptrh, hbase, flags);
    meta_kernel<<<(nnz + 255) / 256, 256, 0, stream>>>(seg, lat, lon, val, qw, ptrh,
                                                       hbase, hbU, nnz, nnzpad, cf3, off6);

    dim3 grid(NBCG, NLAT_OUT);
    disco_kernel<<<grid, NTHREADS, 0, stream>>>(x, cf3, off6, ptrh, hbase, flags,
                                                hbU, hlU, nnzpad, (float*)d_out);
}

// Round 8
// 269.724 us; speedup vs baseline: 1.2338x; 1.2338x over previous
//
#include <hip/hip_runtime.h>

// DISCO S2 conv, equiangular 360x720 -> 180x360, K=3, B*C=128.
// out[bc, k*180+t, p] = sum_{e in seg(k,t)} val[e]*qw[lat[e]] * x[bc, lat[e], (lon[e]-2p-2) mod 720]
//
// Round-8: spread the heavy near-pole segments.
//  - k-split grid (bcg, t, k) = (64, 180, 3) = 34560 blocks (round-7's k-merge
//    reverted: it tripled the heavy-block critical path).
//  - G=2 channels/block + ds_read_b64: same bytes/cycle as b128 but heavy
//    (k,t) work spreads over 2x the CUs -> heavy-CU LDS time halves.
//  - no-decode hot loop (round 6): per-wave baked LDS byte offsets, lane order
//    reversed (p = wid*64+63-lane), 64-slot wrap mirror. Per entry:
//    s_load(uint2) + v_add + ds_read_b64 + 2 v_fmac.
//  - constant-val full rows (t=0/179 poles) collapse to rowsum.
//  - LDS 27.1 KB (MAXR=4) -> 5 blocks/CU = 30 waves/CU.

#define NLAT_IN  360
#define NLON_IN  720
#define NLAT_OUT 180
#define NLON_OUT 360
#define KSIZE    3
#define NSEG     (KSIZE * NLAT_OUT)    // 540
#define CHW      (NLAT_IN * NLON_IN)   // 259200
#define BCTOT    128
#define G        2                     // channels per block
#define NBCG     (BCTOT / G)           // 64
#define MAXR     4
#define PH       10
#define NTHREADS 384
#define NWAVES   (NTHREADS / 64)
#define SLOTS    424                   // 360 + 64 wrap mirror
#define ROWB     (SLOTS * 8)           // 3392 B per row-parity plane (float2 slots)

// ---------------- prep ----------------

// per (s,j): ptrh, hbase/hlast, flags — local binary searches.
__global__ void prep1_kernel(const int* __restrict__ seg, const int* __restrict__ lat,
                             const float* __restrict__ val, int nnz,
                             int* __restrict__ ptrh, int* __restrict__ hbase,
                             int* __restrict__ hlast, int* __restrict__ flags) {
    int idx = blockIdx.x * blockDim.x + threadIdx.x;
    if (idx >= NSEG * PH) return;
    int s = idx / PH, j = idx - s * PH;
    int lo = 0, hi = nnz;
    while (lo < hi) { int m = (lo + hi) >> 1; if (seg[m] < s) lo = m + 1; else hi = m; }
    int e0 = lo;
    lo = e0; hi = nnz;
    while (lo < hi) { int m = (lo + hi) >> 1; if (seg[m] < s + 1) lo = m + 1; else hi = m; }
    int e1 = lo;
    if (e0 >= e1) {
        ptrh[idx] = e0; flags[idx] = 0;
        if (j == 0) { hbase[s] = 1 << 28; hlast[s] = -(1 << 28); }
        return;
    }
    int hb = lat[e0];
    if (j == 0) { hbase[s] = hb; hlast[s] = lat[e1 - 1]; }
    int a;
    { int tg = hb + j; lo = e0; hi = e1;
      while (lo < hi) { int m = (lo + hi) >> 1; if (lat[m] < tg) lo = m + 1; else hi = m; }
      a = lo; }
    ptrh[idx] = a;
    int f = 0;
    if (j < PH - 1) {
        int tg = hb + j + 1; lo = a; hi = e1;
        while (lo < hi) { int m = (lo + hi) >> 1; if (lat[m] < tg) lo = m + 1; else hi = m; }
        int b = lo;
        if (b - a == NLON_IN) {
            float v0 = val[a], v1 = val[a + 240], v2 = val[a + 480];
            float d = fmaxf(fabsf(v0 - v1), fmaxf(fabsf(v0 - v2), fabsf(v1 - v2)));
            f = (d < 1e-5f) ? 1 : 0;
        }
    }
    flags[idx] = f;
}

// mw[wid][e] = { rp*ROWB + b0*8, val*qw } with b0 = (s0 - 64*wid - 63) mod 360,
// rp = ((h - hbase[seg]) % MAXR)*2 + (w&1).
__global__ void prep2_kernel(const int* __restrict__ seg, const int* __restrict__ lat,
                             const int* __restrict__ lon, const float* __restrict__ val,
                             const float* __restrict__ qw, const int* __restrict__ hbase,
                             int nnz, int nnzpad, uint2* __restrict__ mw) {
    int e = blockIdx.x * blockDim.x + threadIdx.x;
    if (e >= nnz) return;
    int wid = blockIdx.y;
    int w = lon[e], h = lat[e];
    int i0 = w >> 1;
    int s0 = i0 ? (i0 - 1) : (NLON_OUT - 1);
    int rp = ((h - hbase[seg[e]]) % MAXR) * 2 + (w & 1);
    int b0 = s0 + 720 - 63 - 64 * wid;
    if (b0 >= 720) b0 -= 720;
    if (b0 >= 360) b0 -= 360;
    mw[(size_t)wid * nnzpad + e] =
        make_uint2((unsigned)(rp * ROWB + (b0 << 3)), __float_as_uint(val[e] * qw[h]));
}

// ---------------- main ----------------

__global__ __launch_bounds__(NTHREADS) void disco_kernel(
    const float* __restrict__ x,
    const uint2* __restrict__ mw,
    const int*   __restrict__ ptrh,
    const int*   __restrict__ hbase,
    const int*   __restrict__ hlast,
    const int*   __restrict__ flags,
    int nnzpad,
    float*       __restrict__ out)
{
    __shared__ float2 ldsx[MAXR * 2][SLOTS];      // 27,136 B -> 5 blocks/CU (wave-limited)
    __shared__ float2 rsum_lds[MAXR];
    __shared__ float2 wred[NWAVES];

    const int tid  = threadIdx.x;
    const int lane = tid & 63, wid = tid >> 6;
    const int p    = wid * 64 + 63 - lane;        // reversed lane -> ascending slots
    const int bc0  = blockIdx.x * G;
    const int ty   = blockIdx.y;
    const int t    = (ty & 1) ? (NLAT_OUT - 1 - (ty >> 1)) : (ty >> 1);  // poles first
    const int s    = blockIdx.z * NLAT_OUT + t;

    const int hb = hbase[s], hl = hlast[s];       // empty: hb > hl
    const uint2* mwp   = mw + (size_t)wid * nnzpad;
    const char*  lbase = (const char*)&ldsx[0][0];
    const int    loff  = lane << 3;

    float a0 = 0.f, a1 = 0.f;

    for (int r0 = hb; r0 <= hl; r0 += MAXR) {
        const int rn = min(MAXR, hl - r0 + 1);
        __syncthreads();                           // prior window readers done
        // ---- stage rows (2 channels, parity-split, 64-slot wrap mirror) ----
        if (tid < NLON_OUT) {
            for (int r = 0; r < rn; ++r) {
                const float* xr = x + (size_t)bc0 * CHW + (size_t)(r0 + r) * NLON_IN + 2 * tid;
                const float2 v0 = *(const float2*)(xr);
                const float2 v1 = *(const float2*)(xr + CHW);
                const float2 ev = make_float2(v0.x, v1.x);
                const float2 ov = make_float2(v0.y, v1.y);
                ldsx[2 * r + 0][tid] = ev;
                ldsx[2 * r + 1][tid] = ov;
                if (tid < SLOTS - NLON_OUT) {      // mirror cols 0..63
                    ldsx[2 * r + 0][NLON_OUT + tid] = ev;
                    ldsx[2 * r + 1][NLON_OUT + tid] = ov;
                }
            }
        }
        __syncthreads();
        // ---- rows of this window ----
        for (int r = 0; r < rn; ++r) {
            const int j = (r0 + r) - hb;
            if (j < 0 || j >= PH - 1) continue;
            const int a = ptrh[s * PH + j], b = ptrh[s * PH + j + 1];
            if (a >= b) continue;                  // uniform
            if (flags[s * PH + j]) {               // constant-val full row -> cf*rowsum
                float2 v = make_float2(0.f, 0.f);
                if (tid < NLON_OUT) {
                    const float2 u0 = ldsx[2 * r][tid], u1 = ldsx[2 * r + 1][tid];
                    v = make_float2(u0.x + u1.x, u0.y + u1.y);
                }
#pragma unroll
                for (int off = 32; off >= 1; off >>= 1) {
                    v.x += __shfl_down(v.x, off);
                    v.y += __shfl_down(v.y, off);
                }
                if (lane == 0) wred[wid] = v;
                __syncthreads();
                if (wid == 0) {
                    float2 u = (lane < NWAVES) ? wred[lane] : make_float2(0.f, 0.f);
#pragma unroll
                    for (int off = 4; off >= 1; off >>= 1) {
                        u.x += __shfl_down(u.x, off);
                        u.y += __shfl_down(u.y, off);
                    }
                    if (lane == 0) rsum_lds[r] = u;
                }
                __syncthreads();
                const float  cf = __uint_as_float(mwp[a].y);
                const float2 rs = rsum_lds[r];
                a0 = fmaf(cf, rs.x, a0);
                a1 = fmaf(cf, rs.y, a1);
                continue;
            }
            // ---- hot loop: s_load meta + v_add + ds_read_b64 + 2 v_fmac ----
#pragma unroll 4
            for (int e = a; e < b; ++e) {
                const uint2  m  = mwp[e];          // wave-uniform -> SGPR
                const float2 xv = *(const float2*)(lbase + m.x + loff);
                const float  cf = __uint_as_float(m.y);
                a0 = fmaf(cf, xv.x, a0);
                a1 = fmaf(cf, xv.y, a1);
            }
        }
    }

    if (p < NLON_OUT) {
        const size_t ob = ((size_t)bc0 * NSEG + s) * NLON_OUT + p;
        out[ob]                           = a0;
        out[ob + (size_t)NSEG * NLON_OUT] = a1;
    }
}

// ---------------- fallback (tiny ws) ----------------

__global__ void segptr_kernel(const int* __restrict__ seg, int nnz, int* __restrict__ ptr) {
    int s = blockIdx.x * blockDim.x + threadIdx.x;
    if (s > NSEG) return;
    if (s == NSEG) { ptr[NSEG] = nnz; return; }
    int lo = 0, hi = nnz;
    while (lo < hi) { int m = (lo + hi) >> 1; if (seg[m] < s) lo = m + 1; else hi = m; }
    ptr[s] = lo;
}

__global__ __launch_bounds__(384) void disco_simple_kernel(
    const float* __restrict__ x, const float* __restrict__ qw,
    const int* __restrict__ lat, const int* __restrict__ lon,
    const float* __restrict__ val, const int* __restrict__ ptr,
    float* __restrict__ out)
{
    const int p = threadIdx.x;
    if (p >= NLON_OUT) return;
    const int kt = blockIdx.x, bc0 = blockIdx.y * 8;
    const int e0 = ptr[kt], e1 = ptr[kt + 1];
    float acc[8];
#pragma unroll
    for (int g = 0; g < 8; ++g) acc[g] = 0.0f;
    const int pw = 2 * p + 2;
    const float* xb = x + (size_t)bc0 * CHW;
    for (int e = e0; e < e1; ++e) {
        const int h = lat[e], w = lon[e];
        const float cf = val[e] * qw[h];
        int col = w - pw; if (col < 0) col += NLON_IN;
        const float* src = xb + h * NLON_IN + col;
#pragma unroll
        for (int g = 0; g < 8; ++g) acc[g] = fmaf(cf, src[(size_t)g * CHW], acc[g]);
    }
    const size_t ob = ((size_t)bc0 * NSEG + kt) * NLON_OUT + p;
#pragma unroll
    for (int g = 0; g < 8; ++g) out[ob + (size_t)g * NSEG * NLON_OUT] = acc[g];
}

// ---------------- launcher ----------------

extern "C" void kernel_launch(void* const* d_in, const int* in_sizes, int n_in,
                              void* d_out, int out_size, void* d_ws, size_t ws_size,
                              hipStream_t stream)
{
    const float* x   = (const float*)d_in[0];   // [2,64,360,720] f32
    const float* qw  = (const float*)d_in[1];   // [360,1] f32
    const int*   seg = (const int*)  d_in[2];   // [nnz] i32 sorted asc
    const int*   lat = (const int*)  d_in[3];
    const int*   lon = (const int*)  d_in[4];
    const float* val = (const float*)d_in[5];
    const int    nnz = in_sizes[2];
    const int    nnzpad = (nnz + 3) & ~3;

    char* w = (char*)d_ws;
    size_t off = 0;
    int* ptrh  = (int*)(w + off); off += (size_t)NSEG * PH * 4;   // 21600
    int* hbase = (int*)(w + off); off += NSEG * 4;
    int* hlast = (int*)(w + off); off += NSEG * 4;
    int* flags = (int*)(w + off); off += (size_t)NSEG * PH * 4;
    off = (off + 15) & ~(size_t)15;
    uint2* mw  = (uint2*)(w + off); off += (size_t)NWAVES * nnzpad * 8;

    if (ws_size < off) {                         // tiny ws: slow-but-correct path
        int* ptr = (int*)d_ws;
        segptr_kernel<<<(NSEG + 1 + 255) / 256, 256, 0, stream>>>(seg, nnz, ptr);
        dim3 grid(NSEG, BCTOT / 8);
        disco_simple_kernel<<<grid, 384, 0, stream>>>(x, qw, lat, lon, val, ptr,
                                                      (float*)d_out);
        return;
    }

    prep1_kernel<<<(NSEG * PH + 255) / 256, 256, 0, stream>>>(seg, lat, val, nnz,
                                                              ptrh, hbase, hlast, flags);
    dim3 pgrid((nnz + 255) / 256, NWAVES);
    prep2_kernel<<<pgrid, 256, 0, stream>>>(seg, lat, lon, val, qw, hbase,
                                            nnz, nnzpad, mw);

    dim3 grid(NBCG, NLAT_OUT, KSIZE);
    disco_kernel<<<grid, NTHREADS, 0, stream>>>(x, mw, ptrh, hbase, hlast, flags,
                                                nnzpad, (float*)d_out);
}